// Round 3
// baseline (374.820 us; speedup 1.0000x reference)
//
#include <hip/hip_runtime.h>

#define NFEAT 42
#define H1 256
#define H2 128
#define H3 64
#define NB 8
#define NA 512
#define NM 100
#define TA 4   // atoms per MLP block

__device__ __forceinline__ float sigmoidf(float z) {
    return 1.0f / (1.0f + __expf(-z));
}

// -------- Kernel 0: transpose weights into workspace (coalesced bwd reads) --------
__global__ __launch_bounds__(256) void transpose_weights(
    const float* __restrict__ W0, const float* __restrict__ W1, const float* __restrict__ W2,
    float* __restrict__ W0T, float* __restrict__ W1T, float* __restrict__ W2T)
{
    int i = blockIdx.x * 256 + threadIdx.x;
    if (i < NFEAT * H1) {           // W0 [42][256] -> W0T [256][42]
        int f = i / H1, k = i - f * H1;
        W0T[k * NFEAT + f] = W0[i];
    }
    if (i < H1 * H2) {              // W1 [256][128] -> W1T [128][256]
        int k = i / H2, j = i - k * H2;
        W1T[j * H1 + k] = W1[i];
    }
    if (i < H2 * H3) {              // W2 [128][64] -> W2T [64][128]
        int j = i / H3, k = i - j * H3;
        W2T[k * H2 + j] = W2[i];
    }
}

// -------- Kernel 1: per-4-atom MLP forward + backward (dE/dx) --------
// Weight loads are scalar but COALESCED across lanes. The k-loops carry
// #pragma unroll so 6-32 independent weight loads issue back-to-back per
// group (vmcnt batching) instead of one dependent load->wait->FMA per
// iteration; this is the latency fix for the L2-resident weight stream.
__global__ __launch_bounds__(256, 4) void mlp_fwd_bwd(
    const float* __restrict__ image,
    const float* __restrict__ W0, const float* __restrict__ b0,
    const float* __restrict__ W1, const float* __restrict__ b1,
    const float* __restrict__ W2, const float* __restrict__ b2,
    const float* __restrict__ W3, const float* __restrict__ b3,
    const float* __restrict__ W0T, const float* __restrict__ W1T, const float* __restrict__ W2T,
    float* __restrict__ Ei,   // [B*N]
    float* __restrict__ dE)   // [B*N, NFEAT]
{
    const int t = threadIdx.x;
    const int atom0 = blockIdx.x * TA;

    __shared__ float sx[TA][NFEAT];
    __shared__ __align__(16) float sh1[TA][H1];
    __shared__ __align__(16) float sh2[TA][H2];
    __shared__ __align__(16) float sh3[TA][H3];
    __shared__ __align__(16) float sd3[TA][H3];
    __shared__ __align__(16) float sd2[TA][H2];
    __shared__ __align__(16) float sd1[TA][H1];

    // stage inputs
    for (int i = t; i < TA * NFEAT; i += 256) {
        int a = i / NFEAT, f = i - a * NFEAT;
        sx[a][f] = image[(atom0 + a) * NFEAT + f];
    }
    __syncthreads();

    // ---- layer 0: 42 -> 256, sigmoid (thread = out neuron, 4 atoms) ----
    {
        float acc[TA] = {0.f, 0.f, 0.f, 0.f};
        #pragma unroll 6
        for (int k = 0; k < NFEAT; ++k) {
            float w = W0[k * H1 + t];
            #pragma unroll
            for (int a = 0; a < TA; ++a) acc[a] += sx[a][k] * w;
        }
        float bb = b0[t];
        #pragma unroll
        for (int a = 0; a < TA; ++a) sh1[a][t] = sigmoidf(acc[a] + bb);
    }
    __syncthreads();

    // ---- layer 1: 256 -> 128, sigmoid (j = t&127, 2 atoms per thread) ----
    {
        const int j = t & 127, a0 = (t >> 7) * 2;
        float acc[2] = {0.f, 0.f};
        #pragma unroll 8
        for (int kk = 0; kk < H1 / 4; ++kk) {
            float w0_ = W1[(4 * kk + 0) * H2 + j];
            float w1_ = W1[(4 * kk + 1) * H2 + j];
            float w2_ = W1[(4 * kk + 2) * H2 + j];
            float w3_ = W1[(4 * kk + 3) * H2 + j];
            #pragma unroll
            for (int a = 0; a < 2; ++a) {
                float4 h = ((const float4*)sh1[a0 + a])[kk];
                acc[a] += h.x * w0_ + h.y * w1_ + h.z * w2_ + h.w * w3_;
            }
        }
        float bb = b1[j];
        #pragma unroll
        for (int a = 0; a < 2; ++a) sh2[a0 + a][j] = sigmoidf(acc[a] + bb);
    }
    __syncthreads();

    // ---- layer 2: 128 -> 64, sigmoid (j = t&63, 1 atom per thread) ----
    {
        const int j = t & 63, a = t >> 6;
        float acc = 0.f;
        #pragma unroll 8
        for (int kk = 0; kk < H2 / 4; ++kk) {
            float w0_ = W2[(4 * kk + 0) * H3 + j];
            float w1_ = W2[(4 * kk + 1) * H3 + j];
            float w2_ = W2[(4 * kk + 2) * H3 + j];
            float w3_ = W2[(4 * kk + 3) * H3 + j];
            float4 h = ((const float4*)sh2[a])[kk];
            acc += h.x * w0_ + h.y * w1_ + h.z * w2_ + h.w * w3_;
        }
        sh3[a][j] = sigmoidf(acc + b2[j]);
    }
    __syncthreads();

    // ---- output layer 64 -> 1 (linear) + sd3; one wave per atom ----
    {
        const int lane = t & 63, a = t >> 6;
        float w = W3[lane];
        float bb = b3[0];
        float h = sh3[a][lane];
        sd3[a][lane] = w * h * (1.f - h);
        float v = w * h;
        #pragma unroll
        for (int off = 32; off > 0; off >>= 1) v += __shfl_down(v, off, 64);
        if (lane == 0) Ei[atom0 + a] = v + bb;
    }
    __syncthreads();

    // ---- bwd: d2 = (W2 @ d3) * h2' (j = t&127, 2 atoms) ----
    {
        const int j = t & 127, a0 = (t >> 7) * 2;
        float acc[2] = {0.f, 0.f};
        #pragma unroll 8
        for (int kk = 0; kk < H3 / 4; ++kk) {
            float w0_ = W2T[(4 * kk + 0) * H2 + j];
            float w1_ = W2T[(4 * kk + 1) * H2 + j];
            float w2_ = W2T[(4 * kk + 2) * H2 + j];
            float w3_ = W2T[(4 * kk + 3) * H2 + j];
            #pragma unroll
            for (int a = 0; a < 2; ++a) {
                float4 d = ((const float4*)sd3[a0 + a])[kk];
                acc[a] += d.x * w0_ + d.y * w1_ + d.z * w2_ + d.w * w3_;
            }
        }
        #pragma unroll
        for (int a = 0; a < 2; ++a) {
            float h = sh2[a0 + a][j];
            sd2[a0 + a][j] = acc[a] * h * (1.f - h);
        }
    }
    __syncthreads();

    // ---- bwd: d1 = (W1 @ d2) * h1' (k = t, all 4 atoms) ----
    {
        float acc[TA] = {0.f, 0.f, 0.f, 0.f};
        #pragma unroll 8
        for (int jj = 0; jj < H2 / 4; ++jj) {
            float w0_ = W1T[(4 * jj + 0) * H1 + t];
            float w1_ = W1T[(4 * jj + 1) * H1 + t];
            float w2_ = W1T[(4 * jj + 2) * H1 + t];
            float w3_ = W1T[(4 * jj + 3) * H1 + t];
            #pragma unroll
            for (int a = 0; a < TA; ++a) {
                float4 d = ((const float4*)sd2[a])[jj];
                acc[a] += d.x * w0_ + d.y * w1_ + d.z * w2_ + d.w * w3_;
            }
        }
        #pragma unroll
        for (int a = 0; a < TA; ++a) {
            float h = sh1[a][t];
            sd1[a][t] = acc[a] * h * (1.f - h);
        }
    }
    __syncthreads();

    // ---- bwd: dE/dx = W0 @ d1 (f = t&63 < 42, 1 atom) ----
    {
        const int f = t & 63, a = t >> 6;
        if (f < NFEAT) {
            float acc = 0.f;
            #pragma unroll 8
            for (int kk = 0; kk < H1 / 4; ++kk) {
                float w0_ = W0T[(4 * kk + 0) * NFEAT + f];
                float w1_ = W0T[(4 * kk + 1) * NFEAT + f];
                float w2_ = W0T[(4 * kk + 2) * NFEAT + f];
                float w3_ = W0T[(4 * kk + 3) * NFEAT + f];
                float4 d = ((const float4*)sd1[a])[kk];
                acc += d.x * w0_ + d.y * w1_ + d.z * w2_ + d.w * w3_;
            }
            dE[(atom0 + a) * NFEAT + f] = acc;
        }
    }
}

// -------- Kernel 2: Etot[b] = sum_i Ei[b,i] --------
__global__ __launch_bounds__(256) void etot_kernel(const float* __restrict__ Ei,
                                                   float* __restrict__ Etot)
{
    const int b = blockIdx.x;
    const int t = threadIdx.x;
    float v = Ei[b * NA + t] + Ei[b * NA + t + 256];
    __shared__ float red[4];
    #pragma unroll
    for (int off = 32; off > 0; off >>= 1) v += __shfl_down(v, off, 64);
    if ((t & 63) == 0) red[t >> 6] = v;
    __syncthreads();
    if (t == 0) Etot[b] = red[0] + red[1] + red[2] + red[3];
}

// -------- Kernel 3: Force via float4-coalesced dfeat stream (round-0 proven) --------
// one block (256 threads) per (b,i); 8 neighbor rows (1008 B) per iteration
__global__ __launch_bounds__(256) void force_kernel(
    const float* __restrict__ dfeat,     // [B,N,M,NFEAT,3] = [bi][100][126]
    const int*   __restrict__ neighbor,  // [B,N,M]
    const float* __restrict__ dE,        // [B,N,NFEAT]
    float* __restrict__ Force)           // [B,N,3]
{
    const int bi = blockIdx.x;
    const int b  = bi >> 9;
    const int t  = threadIdx.x;

    __shared__ int   s_nb[NM];
    __shared__ float s_dE[104 * NFEAT];   // rows 100..103 zero-padded
    __shared__ float s_part[1008];
    __shared__ float s_red[126];

    if (t < NM) s_nb[t] = neighbor[bi * NM + t];
    for (int i = t; i < 4 * NFEAT; i += 256) s_dE[NM * NFEAT + i] = 0.f;
    __syncthreads();

    for (int i = t; i < NM * NFEAT; i += 256) {
        int m = i / NFEAT, f = i - m * NFEAT;
        int n = s_nb[m];
        s_dE[i] = (n > 0) ? dE[((b << 9) + n - 1) * NFEAT + f] : 0.f;
    }
    __syncthreads();

    if (t < 252) {
        const int e4 = 4 * t;
        int off[4];
        #pragma unroll
        for (int c = 0; c < 4; ++c) {
            int ee = e4 + c;
            int r  = ee / 126;            // row within 8-row group
            int e  = ee - r * 126;        // element within row (f*3+d)
            off[c] = r * NFEAT + e / 3;   // s_dE offset relative to m0*NFEAT
        }
        const float* base = dfeat + (size_t)bi * (NM * NFEAT * 3);
        float acc[4] = {0.f, 0.f, 0.f, 0.f};

        for (int m0 = 0; m0 < 96; m0 += 8) {
            float4 v = *(const float4*)(base + m0 * 126 + e4);
            const float* sd = s_dE + m0 * NFEAT;
            acc[0] += v.x * sd[off[0]];
            acc[1] += v.y * sd[off[1]];
            acc[2] += v.z * sd[off[2]];
            acc[3] += v.w * sd[off[3]];
        }
        {   // tail: rows 96..103; rows >=100 hit zero-padded s_dE.
            const int m0 = 96;
            float vv[4];
            if (bi != NB * NA - 1) {
                float4 v = *(const float4*)(base + m0 * 126 + e4);
                vv[0] = v.x; vv[1] = v.y; vv[2] = v.z; vv[3] = v.w;
            } else {
                #pragma unroll
                for (int c = 0; c < 4; ++c) {
                    int r = (e4 + c) / 126;
                    vv[c] = (m0 + r < NM) ? base[m0 * 126 + e4 + c] : 0.f;
                }
            }
            const float* sd = s_dE + m0 * NFEAT;
            #pragma unroll
            for (int c = 0; c < 4; ++c) acc[c] += vv[c] * sd[off[c]];
        }
        #pragma unroll
        for (int c = 0; c < 4; ++c) s_part[e4 + c] = acc[c];
    }
    __syncthreads();

    if (t < 126) {
        float s = 0.f;
        #pragma unroll
        for (int r = 0; r < 8; ++r) s += s_part[r * 126 + t];
        s_red[t] = s;
    }
    __syncthreads();

    if (t < 3) {
        float s = 0.f;
        #pragma unroll
        for (int f = 0; f < NFEAT; ++f) s += s_red[f * 3 + t];
        Force[bi * 3 + t] = s;
    }
}

extern "C" void kernel_launch(void* const* d_in, const int* in_sizes, int n_in,
                              void* d_out, int out_size, void* d_ws, size_t ws_size,
                              hipStream_t stream) {
    const float* image    = (const float*)d_in[0];
    const float* dfeat    = (const float*)d_in[1];
    const int*   neighbor = (const int*)  d_in[2];
    const float* W0 = (const float*)d_in[3];
    const float* b0 = (const float*)d_in[4];
    const float* W1 = (const float*)d_in[5];
    const float* b1 = (const float*)d_in[6];
    const float* W2 = (const float*)d_in[7];
    const float* b2 = (const float*)d_in[8];
    const float* W3 = (const float*)d_in[9];
    const float* b3 = (const float*)d_in[10];

    float* out   = (float*)d_out;
    float* Etot  = out;                    // [8]
    float* Ei    = out + NB;               // [8*512]
    float* Force = out + NB + NB * NA;     // [8*512*3]

    float* dE  = (float*)d_ws;             // [4096*42]
    float* W0T = dE  + NB * NA * NFEAT;    // [256*42]
    float* W1T = W0T + NFEAT * H1;         // [128*256]
    float* W2T = W1T + H1 * H2;            // [64*128]

    transpose_weights<<<(H1 * H2 + 255) / 256, 256, 0, stream>>>(W0, W1, W2, W0T, W1T, W2T);
    mlp_fwd_bwd<<<(NB * NA) / TA, 256, 0, stream>>>(image, W0, b0, W1, b1, W2, b2, W3, b3,
                                                    W0T, W1T, W2T, Ei, dE);
    etot_kernel<<<NB, 256, 0, stream>>>(Ei, Etot);
    force_kernel<<<NB * NA, 256, 0, stream>>>(dfeat, neighbor, dE, Force);
}

// Round 4
// 355.911 us; speedup vs baseline: 1.0531x; 1.0531x over previous
//
#include <hip/hip_runtime.h>

#define NFEAT 42
#define NF_PAD 44
#define H1 256
#define H2 128
#define H3 64
#define NB 8
#define NA 512
#define NM 100
#define TA 4   // atoms per MLP block

__device__ __forceinline__ float sigmoidf(float z) {
    return 1.0f / (1.0f + __expf(-z));
}

// -------- Kernel 0: transpose weights into workspace (coalesced bwd reads) --------
__global__ __launch_bounds__(256) void transpose_weights(
    const float* __restrict__ W0, const float* __restrict__ W1, const float* __restrict__ W2,
    float* __restrict__ W0T, float* __restrict__ W1T, float* __restrict__ W2T)
{
    int i = blockIdx.x * 256 + threadIdx.x;
    if (i < NFEAT * H1) {           // W0 [42][256] -> W0T [256][42]
        int f = i / H1, k = i - f * H1;
        W0T[k * NFEAT + f] = W0[i];
    }
    if (i < H1 * H2) {              // W1 [256][128] -> W1T [128][256]
        int k = i / H2, j = i - k * H2;
        W1T[j * H1 + k] = W1[i];
    }
    if (i < H2 * H3) {              // W2 [128][64] -> W2T [64][128]
        int j = i / H3, k = i - j * H3;
        W2T[k * H2 + j] = W2[i];
    }
}

// -------- Kernel 1: per-4-atom MLP fwd+bwd, 2 output neurons per thread --------
// The MLP is LDS-return-bound: each float4 activation read must feed as many
// FMAs as possible. 2 neurons/thread doubles reuse (8 FMA per ds_read_b128),
// halving grid-total LDS instructions vs the 1-neuron/thread mapping.
// Per-output accumulation order is IDENTICAL to the previous kernel for
// L1/L2/d2/d1/dE (bitwise-same outputs); only L0 regroups (float4 dot).
__global__ __launch_bounds__(256) void mlp_fwd_bwd(
    const float* __restrict__ image,
    const float* __restrict__ W0, const float* __restrict__ b0,
    const float* __restrict__ W1, const float* __restrict__ b1,
    const float* __restrict__ W2, const float* __restrict__ b2,
    const float* __restrict__ W3, const float* __restrict__ b3,
    const float* __restrict__ W0T, const float* __restrict__ W1T, const float* __restrict__ W2T,
    float* __restrict__ Ei,   // [B*N]
    float* __restrict__ dE)   // [B*N, NFEAT]
{
    const int t = threadIdx.x;
    const int atom0 = blockIdx.x * TA;

    __shared__ __align__(16) float sx[TA][NF_PAD];
    __shared__ __align__(16) float sh1[TA][H1];
    __shared__ __align__(16) float sh2[TA][H2];
    __shared__ __align__(16) float sh3[TA][H3];
    __shared__ __align__(16) float sd3[TA][H3];
    __shared__ __align__(16) float sd2[TA][H2];
    __shared__ __align__(16) float sd1[TA][H1];

    // stage inputs (features 42,43 zero-padded)
    for (int i = t; i < TA * NF_PAD; i += 256) {
        int a = i / NF_PAD, f = i - a * NF_PAD;
        sx[a][f] = (f < NFEAT) ? image[(atom0 + a) * NFEAT + f] : 0.f;
    }
    __syncthreads();

    // ---- layer 0: 42 -> 256, sigmoid (thread = neuron, 4 atoms, float4 x) ----
    {
        float acc[TA] = {0.f, 0.f, 0.f, 0.f};
        for (int c = 0; c < 10; ++c) {           // k = 0..39
            float w0 = W0[(4 * c + 0) * H1 + t];
            float w1 = W0[(4 * c + 1) * H1 + t];
            float w2 = W0[(4 * c + 2) * H1 + t];
            float w3 = W0[(4 * c + 3) * H1 + t];
            #pragma unroll
            for (int a = 0; a < TA; ++a) {
                float4 x = ((const float4*)sx[a])[c];
                acc[a] += x.x * w0 + x.y * w1 + x.z * w2 + x.w * w3;
            }
        }
        {                                         // tail k = 40, 41
            float w40 = W0[40 * H1 + t];
            float w41 = W0[41 * H1 + t];
            #pragma unroll
            for (int a = 0; a < TA; ++a)
                acc[a] += sx[a][40] * w40 + sx[a][41] * w41;
        }
        float bb = b0[t];
        #pragma unroll
        for (int a = 0; a < TA; ++a) sh1[a][t] = sigmoidf(acc[a] + bb);
    }
    __syncthreads();

    // ---- layer 1: 256 -> 128, sigmoid. neurons (j0, j0+64), atom t>>6 ----
    {
        const int j0 = t & 63, j1 = j0 + 64, a = t >> 6;
        float acc0 = 0.f, acc1 = 0.f;
        for (int kk = 0; kk < H1 / 4; ++kk) {
            float4 h = ((const float4*)sh1[a])[kk];
            const float* w0r = W1 + (4 * kk + 0) * H2;
            const float* w1r = W1 + (4 * kk + 1) * H2;
            const float* w2r = W1 + (4 * kk + 2) * H2;
            const float* w3r = W1 + (4 * kk + 3) * H2;
            acc0 += h.x * w0r[j0] + h.y * w1r[j0] + h.z * w2r[j0] + h.w * w3r[j0];
            acc1 += h.x * w0r[j1] + h.y * w1r[j1] + h.z * w2r[j1] + h.w * w3r[j1];
        }
        sh2[a][j0] = sigmoidf(acc0 + b1[j0]);
        sh2[a][j1] = sigmoidf(acc1 + b1[j1]);
    }
    __syncthreads();

    // ---- layer 2: 128 -> 64, sigmoid. t<128: neurons (j0, j0+32), atom t>>5 ----
    if (t < 128) {
        const int j0 = t & 31, j1 = j0 + 32, a = t >> 5;
        float acc0 = 0.f, acc1 = 0.f;
        for (int kk = 0; kk < H2 / 4; ++kk) {
            float4 h = ((const float4*)sh2[a])[kk];
            const float* w0r = W2 + (4 * kk + 0) * H3;
            const float* w1r = W2 + (4 * kk + 1) * H3;
            const float* w2r = W2 + (4 * kk + 2) * H3;
            const float* w3r = W2 + (4 * kk + 3) * H3;
            acc0 += h.x * w0r[j0] + h.y * w1r[j0] + h.z * w2r[j0] + h.w * w3r[j0];
            acc1 += h.x * w0r[j1] + h.y * w1r[j1] + h.z * w2r[j1] + h.w * w3r[j1];
        }
        sh3[a][j0] = sigmoidf(acc0 + b2[j0]);
        sh3[a][j1] = sigmoidf(acc1 + b2[j1]);
    }
    __syncthreads();

    // ---- output layer 64 -> 1 (linear) + sd3; one wave per atom ----
    {
        const int lane = t & 63, a = t >> 6;
        float w = W3[lane];
        float bb = b3[0];
        float h = sh3[a][lane];
        sd3[a][lane] = w * h * (1.f - h);
        float v = w * h;
        #pragma unroll
        for (int off = 32; off > 0; off >>= 1) v += __shfl_down(v, off, 64);
        if (lane == 0) Ei[atom0 + a] = v + bb;
    }
    __syncthreads();

    // ---- bwd d2: neurons (j0, j0+64), atom t>>6 ----
    {
        const int j0 = t & 63, j1 = j0 + 64, a = t >> 6;
        float acc0 = 0.f, acc1 = 0.f;
        for (int kk = 0; kk < H3 / 4; ++kk) {
            float4 d = ((const float4*)sd3[a])[kk];
            const float* w0r = W2T + (4 * kk + 0) * H2;
            const float* w1r = W2T + (4 * kk + 1) * H2;
            const float* w2r = W2T + (4 * kk + 2) * H2;
            const float* w3r = W2T + (4 * kk + 3) * H2;
            acc0 += d.x * w0r[j0] + d.y * w1r[j0] + d.z * w2r[j0] + d.w * w3r[j0];
            acc1 += d.x * w0r[j1] + d.y * w1r[j1] + d.z * w2r[j1] + d.w * w3r[j1];
        }
        float h0 = sh2[a][j0];
        float h1 = sh2[a][j1];
        sd2[a][j0] = acc0 * h0 * (1.f - h0);
        sd2[a][j1] = acc1 * h1 * (1.f - h1);
    }
    __syncthreads();

    // ---- bwd d1: outputs (k0, k0+128), atoms (a0, a0+1) ----
    {
        const int k0 = t & 127, k1 = k0 + 128, a0 = (t >> 7) * 2;
        float accA0 = 0.f, accA1 = 0.f, accB0 = 0.f, accB1 = 0.f;
        for (int jj = 0; jj < H2 / 4; ++jj) {
            float4 dA = ((const float4*)sd2[a0])[jj];
            float4 dB = ((const float4*)sd2[a0 + 1])[jj];
            const float* w0r = W1T + (4 * jj + 0) * H1;
            const float* w1r = W1T + (4 * jj + 1) * H1;
            const float* w2r = W1T + (4 * jj + 2) * H1;
            const float* w3r = W1T + (4 * jj + 3) * H1;
            float w00 = w0r[k0], w01 = w0r[k1];
            float w10 = w1r[k0], w11 = w1r[k1];
            float w20 = w2r[k0], w21 = w2r[k1];
            float w30 = w3r[k0], w31 = w3r[k1];
            accA0 += dA.x * w00 + dA.y * w10 + dA.z * w20 + dA.w * w30;
            accA1 += dA.x * w01 + dA.y * w11 + dA.z * w21 + dA.w * w31;
            accB0 += dB.x * w00 + dB.y * w10 + dB.z * w20 + dB.w * w30;
            accB1 += dB.x * w01 + dB.y * w11 + dB.z * w21 + dB.w * w31;
        }
        float h;
        h = sh1[a0][k0];     sd1[a0][k0]     = accA0 * h * (1.f - h);
        h = sh1[a0][k1];     sd1[a0][k1]     = accA1 * h * (1.f - h);
        h = sh1[a0 + 1][k0]; sd1[a0 + 1][k0] = accB0 * h * (1.f - h);
        h = sh1[a0 + 1][k1]; sd1[a0 + 1][k1] = accB1 * h * (1.f - h);
    }
    __syncthreads();

    // ---- bwd dE/dx: t<128, features (f0, f0+21) with f0<21, atom t>>5 ----
    if (t < 128) {
        const int f0 = t & 31, a = t >> 5;
        if (f0 < 21) {
            const int f1 = f0 + 21;
            float acc0 = 0.f, acc1 = 0.f;
            for (int kk = 0; kk < H1 / 4; ++kk) {
                float4 d = ((const float4*)sd1[a])[kk];
                const float* w0r = W0T + (4 * kk + 0) * NFEAT;
                const float* w1r = W0T + (4 * kk + 1) * NFEAT;
                const float* w2r = W0T + (4 * kk + 2) * NFEAT;
                const float* w3r = W0T + (4 * kk + 3) * NFEAT;
                acc0 += d.x * w0r[f0] + d.y * w1r[f0] + d.z * w2r[f0] + d.w * w3r[f0];
                acc1 += d.x * w0r[f1] + d.y * w1r[f1] + d.z * w2r[f1] + d.w * w3r[f1];
            }
            dE[(atom0 + a) * NFEAT + f0] = acc0;
            dE[(atom0 + a) * NFEAT + f1] = acc1;
        }
    }
}

// -------- Kernel 2: Etot[b] = sum_i Ei[b,i] --------
__global__ __launch_bounds__(256) void etot_kernel(const float* __restrict__ Ei,
                                                   float* __restrict__ Etot)
{
    const int b = blockIdx.x;
    const int t = threadIdx.x;
    float v = Ei[b * NA + t] + Ei[b * NA + t + 256];
    __shared__ float red[4];
    #pragma unroll
    for (int off = 32; off > 0; off >>= 1) v += __shfl_down(v, off, 64);
    if ((t & 63) == 0) red[t >> 6] = v;
    __syncthreads();
    if (t == 0) Etot[b] = red[0] + red[1] + red[2] + red[3];
}

// -------- Kernel 3: Force via float4-coalesced dfeat stream (round-0 proven) --------
__global__ __launch_bounds__(256) void force_kernel(
    const float* __restrict__ dfeat,     // [B,N,M,NFEAT,3] = [bi][100][126]
    const int*   __restrict__ neighbor,  // [B,N,M]
    const float* __restrict__ dE,        // [B,N,NFEAT]
    float* __restrict__ Force)           // [B,N,3]
{
    const int bi = blockIdx.x;
    const int b  = bi >> 9;
    const int t  = threadIdx.x;

    __shared__ int   s_nb[NM];
    __shared__ float s_dE[104 * NFEAT];   // rows 100..103 zero-padded
    __shared__ float s_part[1008];
    __shared__ float s_red[126];

    if (t < NM) s_nb[t] = neighbor[bi * NM + t];
    for (int i = t; i < 4 * NFEAT; i += 256) s_dE[NM * NFEAT + i] = 0.f;
    __syncthreads();

    for (int i = t; i < NM * NFEAT; i += 256) {
        int m = i / NFEAT, f = i - m * NFEAT;
        int n = s_nb[m];
        s_dE[i] = (n > 0) ? dE[((b << 9) + n - 1) * NFEAT + f] : 0.f;
    }
    __syncthreads();

    if (t < 252) {
        const int e4 = 4 * t;
        int off[4];
        #pragma unroll
        for (int c = 0; c < 4; ++c) {
            int ee = e4 + c;
            int r  = ee / 126;            // row within 8-row group
            int e  = ee - r * 126;        // element within row (f*3+d)
            off[c] = r * NFEAT + e / 3;   // s_dE offset relative to m0*NFEAT
        }
        const float* base = dfeat + (size_t)bi * (NM * NFEAT * 3);
        float acc[4] = {0.f, 0.f, 0.f, 0.f};

        for (int m0 = 0; m0 < 96; m0 += 8) {
            float4 v = *(const float4*)(base + m0 * 126 + e4);
            const float* sd = s_dE + m0 * NFEAT;
            acc[0] += v.x * sd[off[0]];
            acc[1] += v.y * sd[off[1]];
            acc[2] += v.z * sd[off[2]];
            acc[3] += v.w * sd[off[3]];
        }
        {   // tail: rows 96..103; rows >=100 hit zero-padded s_dE.
            const int m0 = 96;
            float vv[4];
            if (bi != NB * NA - 1) {
                float4 v = *(const float4*)(base + m0 * 126 + e4);
                vv[0] = v.x; vv[1] = v.y; vv[2] = v.z; vv[3] = v.w;
            } else {
                #pragma unroll
                for (int c = 0; c < 4; ++c) {
                    int r = (e4 + c) / 126;
                    vv[c] = (m0 + r < NM) ? base[m0 * 126 + e4 + c] : 0.f;
                }
            }
            const float* sd = s_dE + m0 * NFEAT;
            #pragma unroll
            for (int c = 0; c < 4; ++c) acc[c] += vv[c] * sd[off[c]];
        }
        #pragma unroll
        for (int c = 0; c < 4; ++c) s_part[e4 + c] = acc[c];
    }
    __syncthreads();

    if (t < 126) {
        float s = 0.f;
        #pragma unroll
        for (int r = 0; r < 8; ++r) s += s_part[r * 126 + t];
        s_red[t] = s;
    }
    __syncthreads();

    if (t < 3) {
        float s = 0.f;
        #pragma unroll
        for (int f = 0; f < NFEAT; ++f) s += s_red[f * 3 + t];
        Force[bi * 3 + t] = s;
    }
}

extern "C" void kernel_launch(void* const* d_in, const int* in_sizes, int n_in,
                              void* d_out, int out_size, void* d_ws, size_t ws_size,
                              hipStream_t stream) {
    const float* image    = (const float*)d_in[0];
    const float* dfeat    = (const float*)d_in[1];
    const int*   neighbor = (const int*)  d_in[2];
    const float* W0 = (const float*)d_in[3];
    const float* b0 = (const float*)d_in[4];
    const float* W1 = (const float*)d_in[5];
    const float* b1 = (const float*)d_in[6];
    const float* W2 = (const float*)d_in[7];
    const float* b2 = (const float*)d_in[8];
    const float* W3 = (const float*)d_in[9];
    const float* b3 = (const float*)d_in[10];

    float* out   = (float*)d_out;
    float* Etot  = out;                    // [8]
    float* Ei    = out + NB;               // [8*512]
    float* Force = out + NB + NB * NA;     // [8*512*3]

    float* dE  = (float*)d_ws;             // [4096*42]
    float* W0T = dE  + NB * NA * NFEAT;    // [256*42]
    float* W1T = W0T + NFEAT * H1;         // [128*256]
    float* W2T = W1T + H1 * H2;            // [64*128]

    transpose_weights<<<(H1 * H2 + 255) / 256, 256, 0, stream>>>(W0, W1, W2, W0T, W1T, W2T);
    mlp_fwd_bwd<<<(NB * NA) / TA, 256, 0, stream>>>(image, W0, b0, W1, b1, W2, b2, W3, b3,
                                                    W0T, W1T, W2T, Ei, dE);
    etot_kernel<<<NB, 256, 0, stream>>>(Ei, Etot);
    force_kernel<<<NB * NA, 256, 0, stream>>>(dfeat, neighbor, dE, Force);
}